// Round 9
// baseline (390.300 us; speedup 1.0000x reference)
//
#include <hip/hip_runtime.h>
#include <hip/hip_bf16.h>

#define NH 12
#define HD 64
#define DM 768
#define SEQ 1024
#define BATCH 8

typedef __attribute__((ext_vector_type(8))) short bf16x8;
typedef __attribute__((ext_vector_type(4))) short s16x4;
typedef __attribute__((ext_vector_type(4))) float f32x4;

__device__ __forceinline__ short f2b(float x) {
    unsigned u = __float_as_uint(x);
    u += 0x7fffu + ((u >> 16) & 1u);    // RNE to bf16 (finite values)
    return (short)(u >> 16);
}

#define MFMA(A, B, C) __builtin_amdgcn_mfma_f32_16x16x32_bf16(A, B, C, 0, 0, 0)

// Pl XOR swizzle (T2): spreads 16-row reads across banks; bijective per row.
#define PSWZ(row, col) ((col) ^ (((row) & 7) << 3))

// ---------------------------------------------------------------------------
// f32 -> bf16 conversion (vectorized x4)
// ---------------------------------------------------------------------------
__global__ __launch_bounds__(256) void cvt_f32_bf16(
    const float* __restrict__ in, short* __restrict__ out, int n4)
{
    int i = blockIdx.x * 256 + threadIdx.x;
    if (i < n4) {
        f32x4 v = *(const f32x4*)(in + 4 * (size_t)i);
        s16x4 r;
        r[0] = f2b(v[0]); r[1] = f2b(v[1]); r[2] = f2b(v[2]); r[3] = f2b(v[3]);
        *(s16x4*)(out + 4 * (size_t)i) = r;
    }
}

// ---------------------------------------------------------------------------
// QKV projection, bf16 MFMA. 128x64 tile, 8 waves, BK=64, DOUBLE-BUFFERED
// LDS staging (1 barrier per K-step). z==2 (V) writes transposed into vt.
// ---------------------------------------------------------------------------
__global__ __launch_bounds__(512, 2) void qkv_mfma(
    const short* __restrict__ xb,
    const short* __restrict__ wqb, const float* __restrict__ bq,
    const short* __restrict__ wkb, const float* __restrict__ bk,
    const short* __restrict__ wvb, const float* __restrict__ bv,
    short* __restrict__ qb, short* __restrict__ kb, short* __restrict__ vt)
{
    __shared__ short Xl[2][128][72];   // 36.9 KB
    __shared__ short Wl[2][64][72];    // 18.4 KB

    const int orig = blockIdx.x;                 // 2304 blocks, %8==0
    const int sw   = (orig & 7) * 288 + (orig >> 3);
    const int t    = sw % 36;
    const int by   = t % 12;
    const int z    = t / 12;
    const int bx   = sw / 36;                    // 0..63

    const short* wmat = (z == 0) ? wqb : (z == 1) ? wkb : wvb;
    const float* bias = (z == 0) ? bq : (z == 1) ? bk : bv;

    const int i0   = bx * 128;
    const int col0 = by * 64;
    const int tid  = threadIdx.x;
    const int lane = tid & 63;
    const int w    = tid >> 6;
    const int lg   = lane >> 4;
    const int lc   = lane & 15;

    const int sr = tid >> 3, scx = (tid & 7) * 8;

    auto stage = [&](int k0, int buf) {
        *(bf16x8*)&Xl[buf][sr][scx] =
            *(const bf16x8*)&xb[(size_t)(i0 + sr) * DM + k0 + scx];
        *(bf16x8*)&Xl[buf][sr + 64][scx] =
            *(const bf16x8*)&xb[(size_t)(i0 + 64 + sr) * DM + k0 + scx];
        *(bf16x8*)&Wl[buf][sr][scx] =
            *(const bf16x8*)&wmat[(size_t)(col0 + sr) * DM + k0 + scx];
    };

    f32x4 acc[4] = {};
    stage(0, 0);
    __syncthreads();

    for (int ks = 0; ks < 12; ++ks) {
        const int cur = ks & 1;
        if (ks < 11) stage((ks + 1) * 64, cur ^ 1);   // dbuf: no read hazard
        #pragma unroll
        for (int kh = 0; kh < 2; ++kh) {
            const bf16x8 a = *(const bf16x8*)&Xl[cur][w * 16 + lc][kh * 32 + lg * 8];
            #pragma unroll
            for (int n = 0; n < 4; ++n) {
                const bf16x8 bfr = *(const bf16x8*)&Wl[cur][n * 16 + lc][kh * 32 + lg * 8];
                acc[n] = MFMA(a, bfr, acc[n]);
            }
        }
        __syncthreads();   // next-buf writes visible; cur reads done before reuse
    }

    if (z < 2) {
        short* outp = (z == 0) ? qb : kb;
        #pragma unroll
        for (int n = 0; n < 4; ++n) {
            const int c = col0 + n * 16 + lc;
            const float bi = bias[c];
            #pragma unroll
            for (int rr = 0; rr < 4; ++rr) {
                const int r = i0 + w * 16 + lg * 4 + rr;
                outp[(size_t)r * DM + c] = f2b(acc[n][rr] + bi);
            }
        }
    } else {
        #pragma unroll
        for (int n = 0; n < 4; ++n) {
            const int c = col0 + n * 16 + lc;     // o = h*64 + d
            const int h = c >> 6, d = c & 63;
            const float bi = bias[c];
            #pragma unroll
            for (int rr = 0; rr < 4; ++rr) {
                const int r  = i0 + w * 16 + lg * 4 + rr;   // b*1024 + j
                const int bb = r >> 10, j = r & 1023;
                vt[(((size_t)bb * NH + h) * HD + d) * SEQ + j] = f2b(acc[n][rr] + bi);
            }
        }
    }
}

// ---------------------------------------------------------------------------
// Flash MFMA attention, within-wave softmax, register-diet edition.
// Block = 128 Q-rows x (h,b), 8 waves; wave w owns rows [w*16,w*16+16).
// Per 64-j chunk: K from double-buffered LDS (1 barrier/chunk); demb
// B-frags direct from global (L2-hot, 256 KB shared); T bias tiles ->
// per-wave LDS f32 (frees 20 VGPRs; gather = plain LDS read); P in
// XOR-swizzled per-wave LDS; PV reads V^T direct from global.
// ---------------------------------------------------------------------------
__global__ __launch_bounds__(512, 4) void attn_flash(
    const short* __restrict__ qb, const short* __restrict__ kb,
    const short* __restrict__ vt, const short* __restrict__ deb,
    float* __restrict__ out)
{
    const int orig = blockIdx.x;                 // 768 blocks, %8==0
    const int sw   = (orig & 7) * 96 + (orig >> 3);   // XCD <-> batch
    const int bx   = sw & 7;
    const int rest = sw >> 3;
    const int h    = rest % NH;
    const int b    = rest / NH;

    const int i0   = bx * 128;
    const int tid  = threadIdx.x;
    const int lane = tid & 63;
    const int w    = tid >> 6;        // 0..7
    const int wR   = w * 16;
    const int lg   = lane >> 4;
    const int lc   = lane & 15;

    __shared__ short Kl[2][64][72];   // 18.4 KB (double-buffered K chunk)
    __shared__ float Tl[8][16][84];   // 43.0 KB (per-wave bias tiles, f32)
    __shared__ short Pl[8][16][64];   // 16.4 KB (per-wave P, XOR-swizzled)

    // Q A-fragments (held whole kernel)
    const short* qrow = qb + ((size_t)(b * SEQ + i0 + wR + lc)) * DM + h * HD;
    const bf16x8 A0 = *(const bf16x8*)(qrow + lg * 8);
    const bf16x8 A1 = *(const bf16x8*)(qrow + 32 + lg * 8);

    const short* kbase = kb + (size_t)(b * SEQ) * DM + h * HD;
    const short* vbase = vt + ((size_t)(b * NH + h) * HD) * SEQ;

    const int sr = tid >> 3, scx = (tid & 7) * 8;
    auto stage = [&](int jc, int buf) {
        *(bf16x8*)&Kl[buf][sr][scx] =
            *(const bf16x8*)&kbase[(size_t)(jc + sr) * DM + scx];
    };

    float m[4], l[4];
    f32x4 O0 = {0.f,0.f,0.f,0.f}, O1 = {0.f,0.f,0.f,0.f};
    f32x4 O2 = {0.f,0.f,0.f,0.f}, O3 = {0.f,0.f,0.f,0.f};
    #pragma unroll
    for (int rr = 0; rr < 4; ++rr) { m[rr] = -1e30f; l[rr] = 0.f; }

    stage(0, 0);
    __syncthreads();

    for (int c = 0; c < 16; ++c) {
        const int jc  = c * 64;
        const int cur = c & 1;
        if (c < 15) stage(jc + 64, cur ^ 1);   // dbuf: safe anywhere in chunk

        // ---- T bias tiles: MFMA(Q, demb) direct from global -> per-wave LDS
        const int wb = i0 + wR - jc + 960;     // this wave's window base
        #pragma unroll
        for (int t = 0; t < 5; ++t) {
            int drow = wb + t * 16 + lc;
            if (t == 4) drow = min(drow, 2046);    // col 79 never read
            const short* dp = deb + (size_t)drow * HD;
            f32x4 a = {0.f,0.f,0.f,0.f};
            a = MFMA(A0, *(const bf16x8*)(dp + lg * 8), a);
            a = MFMA(A1, *(const bf16x8*)(dp + 32 + lg * 8), a);
            #pragma unroll
            for (int rr = 0; rr < 4; ++rr)
                Tl[w][lg * 4 + rr][t * 16 + lc] = a[rr];
        }

        // ---- QK tiles from staged K ----
        f32x4 sv[4];
        #pragma unroll
        for (int jt = 0; jt < 4; ++jt) {
            f32x4 s = {0.f,0.f,0.f,0.f};
            s = MFMA(A0, *(const bf16x8*)&Kl[cur][jt * 16 + lc][lg * 8], s);
            s = MFMA(A1, *(const bf16x8*)&Kl[cur][jt * 16 + lc][32 + lg * 8], s);
            sv[jt] = s;
        }

        // ---- bias gather (per-wave LDS; same-wave DS in-order) + max ----
        float mw[4] = {-1e30f, -1e30f, -1e30f, -1e30f};
        #pragma unroll
        for (int jt = 0; jt < 4; ++jt) {
            #pragma unroll
            for (int rr = 0; rr < 4; ++rr) {
                const int row  = lg * 4 + rr;
                const int loff = 63 + row - jt * 16 - lc;   // 0..78
                sv[jt][rr] += Tl[w][row][loff];
                mw[rr] = fmaxf(mw[rr], sv[jt][rr]);
            }
        }

        // ---- within-wave online softmax ----
        float scale[4];
        #pragma unroll
        for (int rr = 0; rr < 4; ++rr) {
            const int row = lg * 4 + rr;
            float v = mw[rr];
            v = fmaxf(v, __shfl_xor(v, 1, 64));
            v = fmaxf(v, __shfl_xor(v, 2, 64));
            v = fmaxf(v, __shfl_xor(v, 4, 64));
            v = fmaxf(v, __shfl_xor(v, 8, 64));
            const float mn = fmaxf(m[rr], v);
            scale[rr] = __expf((m[rr] - mn) * 0.125f);
            m[rr] = mn;
            float s = 0.f;
            #pragma unroll
            for (int jt = 0; jt < 4; ++jt) {
                const float p = __expf((sv[jt][rr] - mn) * 0.125f);
                Pl[w][row][PSWZ(row, jt * 16 + lc)] = f2b(p);
                s += p;
            }
            s += __shfl_xor(s, 1, 64);
            s += __shfl_xor(s, 2, 64);
            s += __shfl_xor(s, 4, 64);
            s += __shfl_xor(s, 8, 64);
            l[rr] = l[rr] * scale[rr] + s;
        }

        // ---- O rescale + PV (P from swizzled LDS, V^T direct global) ----
        #pragma unroll
        for (int rr = 0; rr < 4; ++rr) {
            O0[rr] *= scale[rr]; O1[rr] *= scale[rr];
            O2[rr] *= scale[rr]; O3[rr] *= scale[rr];
        }
        #pragma unroll
        for (int ks = 0; ks < 2; ++ks) {
            const bf16x8 Af = *(const bf16x8*)&Pl[w][lc][PSWZ(lc, ks * 32 + lg * 8)];
            const size_t vo = jc + ks * 32 + lg * 8;
            O0 = MFMA(Af, *(const bf16x8*)&vbase[(size_t)( 0 + lc) * SEQ + vo], O0);
            O1 = MFMA(Af, *(const bf16x8*)&vbase[(size_t)(16 + lc) * SEQ + vo], O1);
            O2 = MFMA(Af, *(const bf16x8*)&vbase[(size_t)(32 + lc) * SEQ + vo], O2);
            O3 = MFMA(Af, *(const bf16x8*)&vbase[(size_t)(48 + lc) * SEQ + vo], O3);
        }
        __syncthreads();   // staged chunk c+1 visible; spaces Kl buffer reuse
    }

    #pragma unroll
    for (int rr = 0; rr < 4; ++rr) {
        const size_t rowoff = ((size_t)(b * SEQ + i0 + wR + lg * 4 + rr)) * DM + h * HD;
        const float inv = 1.0f / l[rr];
        out[rowoff +  0 + lc] = O0[rr] * inv;
        out[rowoff + 16 + lc] = O1[rr] * inv;
        out[rowoff + 32 + lc] = O2[rr] * inv;
        out[rowoff + 48 + lc] = O3[rr] * inv;
    }
}

// ---------------------------------------------------------------------------
extern "C" void kernel_launch(void* const* d_in, const int* in_sizes, int n_in,
                              void* d_out, int out_size, void* d_ws, size_t ws_size,
                              hipStream_t stream) {
    const float* x  = (const float*)d_in[0];
    const float* wq = (const float*)d_in[1];
    const float* bq = (const float*)d_in[2];
    const float* wk = (const float*)d_in[3];
    const float* bk = (const float*)d_in[4];
    const float* wv = (const float*)d_in[5];
    const float* bv = (const float*)d_in[6];
    const float* de = (const float*)d_in[7];
    float* out = (float*)d_out;

    // bf16 workspace layout (~58 MB total, all 16B-aligned)
    const size_t NX = (size_t)BATCH * SEQ * DM;   // 6,291,456
    const size_t NW = (size_t)DM * DM;            //   589,824
    const size_t ND = 2047 * HD;                  //   131,008
    short* xb  = (short*)d_ws;
    short* wqb = xb  + NX;
    short* wkb = wqb + NW;
    short* wvb = wkb + NW;
    short* deb = wvb + NW;
    short* qbw = deb + ND;
    short* kbw = qbw + NX;
    short* vtw = kbw + NX;

    cvt_f32_bf16<<<(int)((NX / 4 + 255) / 256), 256, 0, stream>>>(x,  xb,  (int)(NX / 4));
    cvt_f32_bf16<<<(int)((NW / 4 + 255) / 256), 256, 0, stream>>>(wq, wqb, (int)(NW / 4));
    cvt_f32_bf16<<<(int)((NW / 4 + 255) / 256), 256, 0, stream>>>(wk, wkb, (int)(NW / 4));
    cvt_f32_bf16<<<(int)((NW / 4 + 255) / 256), 256, 0, stream>>>(wv, wvb, (int)(NW / 4));
    cvt_f32_bf16<<<(int)((ND / 4 + 255) / 256), 256, 0, stream>>>(de, deb, (int)(ND / 4));

    qkv_mfma<<<2304, 512, 0, stream>>>(xb, wqb, bq, wkb, bk, wvb, bv,
                                       qbw, kbw, vtw);
    attn_flash<<<768, 512, 0, stream>>>(qbw, kbw, vtw, deb, out);
}